// Round 8
// baseline (593.584 us; speedup 1.0000x reference)
//
#include <hip/hip_runtime.h>

// VanillaRNN: S=512, I=1, H=256, C=10, B=2048, fp32 in/out.
// R14: anti-phase wave pairing. Empirical law from R5/R6/R13: step time =
// pipe work (LDS reads dominate: 96cyc x waves) + ~900cyc per-wave serial
// latency that only a CO-RESIDENT wave hides (1/SIMD: 1712/1800; 2/SIMD:
// 1366-1540). R13 proved 64-row waves compile spill-free (156 VGPR) and
// halve LDS traffic; R6 proved 2/SIMD TLP. Combine: 8 waves = 2 independent
// 16-col groups (G0=waves 0-3, G1=waves 4-7; each SIMD hosts one of each),
// 64 rows/wave, TWO barriers/step in OPPOSITE phases:
//   interval A: G0 {8x ds_read_b128 + 32 MFMA}   G1 {tanh + write}
//   interval B: G0 {tanh + write}                G1 {read + MFMA}
// Partner's trans/VALU phase hides the active wave's LDS/MFMA latency and
// vice versa. Single h-buffer per group (read-in-A/write-in-B are barrier-
// separated: RAW and WAR both safe) -> 16.9KB hT. Register discipline vs
// R10's spill: single 8-deep chain per mt (acc[4]=16 regs across barrier,
// not 32), bfr dies in consumption order; peak ~225 < 256 @ 2 waves/EU.
// Fallback (pre-declared): if >=291us or spill (VGPR~128 + WRITE_SIZE>>80KB)
// -> R6/R12 at 291us is the structural plateau.
// Kept: linear pitch-264 hT (bank-even, lane-invariant strides, R12),
// x folded into MFMA C-operand, x prefetch, weights pre-scaled by 2*log2e:
// tanh = 1 - 2*rcp(exp2(s)+1).

#define SEQ    512
#define HID    256
#define NCLS   10
#define BN     32     // 2 groups x 16 cols
#define NT     512    // 8 waves
#define XP     33     // xs row pitch
#define PITCH  264    // f16 per column (528 B = 33 x 16B chunks)

typedef _Float16 f16x8 __attribute__((ext_vector_type(8)));
typedef _Float16 f16x4 __attribute__((ext_vector_type(4)));
typedef float    f32x4 __attribute__((ext_vector_type(4)));

#define MFMA16(a, b, c) __builtin_amdgcn_mfma_f32_16x16x32_f16(a, b, c, 0, 0, 0)

__global__ __launch_bounds__(NT, 2)
__attribute__((amdgpu_waves_per_eu(2, 2)))
void rnn_mfma(
    const float* __restrict__ x,     // [B, S]
    const float* __restrict__ W_hx,  // [H]
    const float* __restrict__ W_hh,  // [H, H]
    const float* __restrict__ W_ph,  // [C, H]
    const float* __restrict__ b_h,   // [H]
    const float* __restrict__ b_p,   // [C]
    float* __restrict__ out)         // [B, C]
{
    // hT[g][n][j]: group g's h, col n (local), row j, linear, pitch 264.
    __shared__ __align__(16) _Float16 hT[2][16][PITCH];   // 16.9 KB
    __shared__ __align__(16) float xs[SEQ + 2][XP];       // 67.8 KB

    const int tid  = threadIdx.x;
    const int lane = tid & 63;
    const int wave = tid >> 6;       // 0..7
    const int g    = wave >> 2;      // group 0/1 (col block)
    const int w4   = wave & 3;       // row-quarter within group
    const int n16  = lane & 15;
    const int quad = lane >> 4;      // 0..3
    const int col  = g * 16 + n16;   // batch col within block
    const int b0   = blockIdx.x * BN;

    const float SC = 2.885390081777926814f;   // 2*log2(e)

    // ---- A-frags: 4 m-tiles, rows w4*64 + mt*16 + n16, scaled, f16 ----
    f16x8 afrag[4][8];               // 128 VGPRs
#pragma unroll
    for (int mt = 0; mt < 4; ++mt) {
        const int row = w4 * 64 + mt * 16 + n16;
#pragma unroll
        for (int ks = 0; ks < 8; ++ks) {
            const float4* p = (const float4*)&W_hh[row * HID + ks * 32 + quad * 8];
            float4 u = p[0], v = p[1];
            f16x8 a;
            a[0] = (_Float16)(SC * u.x); a[1] = (_Float16)(SC * u.y);
            a[2] = (_Float16)(SC * u.z); a[3] = (_Float16)(SC * u.w);
            a[4] = (_Float16)(SC * v.x); a[5] = (_Float16)(SC * v.y);
            a[6] = (_Float16)(SC * v.z); a[7] = (_Float16)(SC * v.w);
            afrag[mt][ks] = a;
        }
    }
    // D rows for this lane: row = w4*64 + mt*16 + quad*4 + r
    f32x4 bias[4], wxv[4];
#pragma unroll
    for (int mt = 0; mt < 4; ++mt)
#pragma unroll
        for (int r = 0; r < 4; ++r) {
            const int row = w4 * 64 + mt * 16 + quad * 4 + r;
            bias[mt][r] = SC * b_h[row];
            wxv[mt][r]  = SC * W_hx[row];
        }

    // ---- linear byte bases within this group's buffer ----
    char* hbb = (char*)hT[g];
    const int rbase = n16 * (PITCH * 2) + quad * 16;              // + ks*64
    const int wbase = n16 * (PITCH * 2) + w4 * 128 + quad * 8;    // + mt*32

    // ---- stage xs[t][n] = x[b0+n][t] ----
    for (int i = tid; i < BN * SEQ / 4; i += NT) {
        const int n = i >> 7, t4 = (i & 127) * 4;
        float4 v = *(const float4*)&x[(b0 + n) * SEQ + t4];
        xs[t4 + 0][n] = v.x; xs[t4 + 1][n] = v.y;
        xs[t4 + 2][n] = v.z; xs[t4 + 3][n] = v.w;
    }
    // ---- h0 = 0 (both groups, single buffer each) ----
    for (int i = tid; i < 2 * 16 * PITCH / 2; i += NT) ((float*)hT)[i] = 0.0f;
    __syncthreads();

    float xv = xs[0][col];   // prefetched x_t
    f32x4 acc[4];            // carried across ONE barrier (16 regs)

#define READ_MFMA(T)                                                          \
    {                                                                         \
        const float xnxt = xs[(T) + 1][col];                                  \
        f16x8 q0 = *(const f16x8*)(hbb + rbase + 0 * 64);                     \
        f16x8 q1 = *(const f16x8*)(hbb + rbase + 1 * 64);                     \
        f16x8 q2 = *(const f16x8*)(hbb + rbase + 2 * 64);                     \
        f16x8 q3 = *(const f16x8*)(hbb + rbase + 3 * 64);                     \
        f16x8 q4 = *(const f16x8*)(hbb + rbase + 4 * 64);                     \
        f16x8 q5 = *(const f16x8*)(hbb + rbase + 5 * 64);                     \
        f16x8 q6 = *(const f16x8*)(hbb + rbase + 6 * 64);                     \
        f16x8 q7 = *(const f16x8*)(hbb + rbase + 7 * 64);                     \
        _Pragma("unroll")                                                     \
        for (int mt = 0; mt < 4; ++mt) {                                      \
            f32x4 c0;                                                         \
            _Pragma("unroll")                                                 \
            for (int r = 0; r < 4; ++r)                                       \
                c0[r] = fmaf(wxv[mt][r], xv, bias[mt][r]);                    \
            acc[mt] = MFMA16(afrag[mt][0], q0, c0);                           \
        }                                                                     \
        _Pragma("unroll")                                                     \
        for (int mt = 0; mt < 4; ++mt)                                        \
            acc[mt] = MFMA16(afrag[mt][1], q1, acc[mt]);                      \
        _Pragma("unroll")                                                     \
        for (int mt = 0; mt < 4; ++mt)                                        \
            acc[mt] = MFMA16(afrag[mt][2], q2, acc[mt]);                      \
        _Pragma("unroll")                                                     \
        for (int mt = 0; mt < 4; ++mt)                                        \
            acc[mt] = MFMA16(afrag[mt][3], q3, acc[mt]);                      \
        _Pragma("unroll")                                                     \
        for (int mt = 0; mt < 4; ++mt)                                        \
            acc[mt] = MFMA16(afrag[mt][4], q4, acc[mt]);                      \
        _Pragma("unroll")                                                     \
        for (int mt = 0; mt < 4; ++mt)                                        \
            acc[mt] = MFMA16(afrag[mt][5], q5, acc[mt]);                      \
        _Pragma("unroll")                                                     \
        for (int mt = 0; mt < 4; ++mt)                                        \
            acc[mt] = MFMA16(afrag[mt][6], q6, acc[mt]);                      \
        _Pragma("unroll")                                                     \
        for (int mt = 0; mt < 4; ++mt)                                        \
            acc[mt] = MFMA16(afrag[mt][7], q7, acc[mt]);                      \
        xv = xnxt;                                                            \
    }

#define TANH_WRITE()                                                          \
    {                                                                         \
        _Pragma("unroll")                                                     \
        for (int mt = 0; mt < 4; ++mt) {                                      \
            f16x4 h4;                                                         \
            _Pragma("unroll")                                                 \
            for (int r = 0; r < 4; ++r) {                                     \
                float ex = __builtin_amdgcn_exp2f(acc[mt][r]);                \
                float rc = __builtin_amdgcn_rcpf(ex + 1.0f);                  \
                h4[r] = (_Float16)(1.0f - 2.0f * rc);                         \
            }                                                                 \
            *(f16x4*)(hbb + wbase + mt * 32) = h4;                            \
        }                                                                     \
    }

    for (int t = 0; t < SEQ; ++t) {
        // interval A: G0 reads h_t + MFMAs; G1 finishes h_t (tanh+write)
        if (g == 0) {
            READ_MFMA(t)
        } else if (t > 0) {
            TANH_WRITE()
        }
        __syncthreads();
        // interval B: G0 finishes h_{t+1}; G1 reads h_t + MFMAs
        if (g == 0) {
            TANH_WRITE()
        } else {
            READ_MFMA(t)
        }
        __syncthreads();
    }
    // tail: G1 writes its h_512
    if (g == 1) { TANH_WRITE() }
    __syncthreads();

#undef READ_MFMA
#undef TANH_WRITE

    // ---- output: out[b][c] = b_p[c] + sum_j W_ph[c][j] * h_final[j][b] ----
    // final h of local col b: hT[b>>4][b&15][j], linear
    if (tid < BN * NCLS) {
        const int b = tid / NCLS, c = tid % NCLS;
        float sum = b_p[c];
        const _Float16* hp = hT[b >> 4][b & 15];
        for (int j = 0; j < HID; ++j)
            sum += W_ph[c * HID + j] * (float)hp[j];
        out[(b0 + b) * NCLS + c] = sum;
    }
}

extern "C" void kernel_launch(void* const* d_in, const int* in_sizes, int n_in,
                              void* d_out, int out_size, void* d_ws, size_t ws_size,
                              hipStream_t stream) {
    const float* x    = (const float*)d_in[0];
    const float* W_hx = (const float*)d_in[1];
    const float* W_hh = (const float*)d_in[2];
    const float* W_ph = (const float*)d_in[3];
    const float* b_h  = (const float*)d_in[4];
    const float* b_p  = (const float*)d_in[5];
    float* out = (float*)d_out;

    rnn_mfma<<<dim3(2048 / BN), dim3(NT), 0, stream>>>(
        x, W_hx, W_hh, W_ph, b_h, b_p, out);
}